// Round 5
// baseline (1828.759 us; speedup 1.0000x reference)
//
#include <hip/hip_runtime.h>

#define DIM 256
#define N_REL 8

typedef __attribute__((ext_vector_type(8))) short short8_t;
typedef __attribute__((ext_vector_type(4))) float float4_t;

// ---------------- bf16 helpers (manual, RNE) ----------------
__device__ inline unsigned short f2bf(float f) {
    unsigned u = __float_as_uint(f);
    u += 0x7FFFu + ((u >> 16) & 1u);
    return (unsigned short)(u >> 16);
}
__device__ inline float bf2f(unsigned short h) {
    return __uint_as_float(((unsigned)h) << 16);
}

// ---------------- cast / transpose prep kernels ----------------
__global__ __launch_bounds__(256) void cast_f32_bf16(
    const float* __restrict__ in, unsigned short* __restrict__ out, int n4)
{
    const int i = blockIdx.x * blockDim.x + threadIdx.x;
    if (i >= n4) return;
    const float4 v = ((const float4*)in)[i];
    ushort4 o;
    o.x = f2bf(v.x); o.y = f2bf(v.y); o.z = f2bf(v.z); o.w = f2bf(v.w);
    ((ushort4*)out)[i] = o;
}

// W[rel][in][out] f32  ->  Wt[rel][out][in] bf16
__global__ __launch_bounds__(256) void transpose_cast_w(
    const float* __restrict__ W, unsigned short* __restrict__ Wt)
{
    __shared__ float tile[32][33];
    const int rel = blockIdx.z;
    const int i0 = blockIdx.x * 32, o0 = blockIdx.y * 32;
    const int tx = threadIdx.x, ty = threadIdx.y;   // (32, 8)
    const float* Wr = W + (size_t)rel * DIM * DIM;
    unsigned short* Wtr = Wt + (size_t)rel * DIM * DIM;
#pragma unroll
    for (int j = 0; j < 4; j++)
        tile[ty + 8 * j][tx] = Wr[(size_t)(i0 + ty + 8 * j) * DIM + o0 + tx];
    __syncthreads();
#pragma unroll
    for (int j = 0; j < 4; j++)
        Wtr[(size_t)(o0 + ty + 8 * j) * DIM + i0 + tx] = f2bf(tile[tx][ty + 8 * j]);
}

// ---------------------------------------------------------------------------
// Yall[rel][M][256] = relu(Xb @ W[rel] + bias) in bf16.
// Tile 128x128, BK=32, 4 waves of 64x64 (4x4 mfma_f32_16x16x32_bf16).
// Epilogue staged through LDS -> full 256B coalesced row-segment stores.
// ---------------------------------------------------------------------------
__global__ __launch_bounds__(256) void gemm_mfma_bias_relu(
    const unsigned short* __restrict__ Xb,    // [M][256]
    const unsigned short* __restrict__ Wtb,   // [R][256out][256in]
    const float* __restrict__ bias,           // [256]
    unsigned short* __restrict__ Yall, int M)
{
    __shared__ __align__(16) short smem[10240]; // As 5120 | Bs 5120 shorts
    short* As = smem;
    short* Bs = smem + 5120;

    const int m0 = blockIdx.x * 128;
    const int n0 = blockIdx.y * 128;
    const int rel = blockIdx.z;

    const unsigned short* Wt = Wtb + (size_t)rel * DIM * DIM;
    unsigned short* Y = Yall + (size_t)rel * M * DIM;

    const int t = threadIdx.x;
    const int lane = t & 63;
    const int w = t >> 6;
    const int wr = w & 1, wc = w >> 1;
    const int r = lane & 15, q = lane >> 4;

    const int rowA0 = t >> 2;     // 0..63 (+64 second half)
    const int segA0 = t & 3;      // 16B segment within 64B row

    float4_t acc[4][4];
#pragma unroll
    for (int i = 0; i < 4; i++)
#pragma unroll
        for (int j = 0; j < 4; j++) {
            float4_t z = {0.f, 0.f, 0.f, 0.f};
            acc[i][j] = z;
        }

    short8_t ra[2], rb[2];
    const short8_t zero8 = {0, 0, 0, 0, 0, 0, 0, 0};

#define LOAD_TILES(ks)                                                            \
    {                                                                             \
        const int k0_ = (ks) * 32;                                                \
        _Pragma("unroll")                                                         \
        for (int h = 0; h < 2; h++) {                                             \
            const int row_ = rowA0 + h * 64;                                      \
            const int m_ = m0 + row_;                                             \
            if (m_ < M)                                                           \
                ra[h] = *(const short8_t*)(Xb + (size_t)m_ * DIM + k0_ + segA0 * 8); \
            else                                                                  \
                ra[h] = zero8;                                                    \
            rb[h] = *(const short8_t*)(Wt + (size_t)(n0 + row_) * DIM + k0_ + segA0 * 8); \
        }                                                                         \
    }

    LOAD_TILES(0);
#pragma unroll 1
    for (int ks = 0; ks < 8; ks++) {
#pragma unroll
        for (int h = 0; h < 2; h++) {
            const int row_ = rowA0 + h * 64;
            *(short8_t*)&As[row_ * 40 + segA0 * 8] = ra[h];
            *(short8_t*)&Bs[row_ * 40 + segA0 * 8] = rb[h];
        }
        __syncthreads();
        if (ks < 7) LOAD_TILES(ks + 1);

        short8_t af[4], bf[4];
#pragma unroll
        for (int mi = 0; mi < 4; mi++)
            af[mi] = *(const short8_t*)&As[(wr * 64 + mi * 16 + r) * 40 + q * 8];
#pragma unroll
        for (int ni = 0; ni < 4; ni++)
            bf[ni] = *(const short8_t*)&Bs[(wc * 64 + ni * 16 + r) * 40 + q * 8];
#pragma unroll
        for (int mi = 0; mi < 4; mi++)
#pragma unroll
            for (int ni = 0; ni < 4; ni++)
                acc[mi][ni] = __builtin_amdgcn_mfma_f32_16x16x32_bf16(
                    af[mi], bf[ni], acc[mi][ni], 0, 0, 0);
        __syncthreads();
    }
#undef LOAD_TILES

    // -------- epilogue: bias+relu, LDS-staged coalesced bf16 stores --------
    // staging: 32 rows x 128 cols bf16, stride 136 shorts. q-groups hit
    // disjoint bank octets; <=2-way everywhere (free per m136).
    short* St = smem;   // 32*136 = 4352 shorts, aliases As/Bs (K-loop done)

    float bv[4];
#pragma unroll
    for (int ni = 0; ni < 4; ni++)
        bv[ni] = bias[n0 + wc * 64 + ni * 16 + r];

#pragma unroll 1
    for (int mi = 0; mi < 4; mi++) {
#pragma unroll
        for (int ni = 0; ni < 4; ni++) {
#pragma unroll
            for (int e = 0; e < 4; e++) {
                const int rl = wr * 16 + q * 4 + e;
                const int col = wc * 64 + ni * 16 + r;
                St[rl * 136 + col] = f2bf(fmaxf(acc[mi][ni][e] + bv[ni], 0.f));
            }
        }
        __syncthreads();
        // readout: 512 chunks of 8 shorts (16B); each thread stores 2
#pragma unroll
        for (int j = 0; j < 2; j++) {
            const int id = t + 256 * j;
            const int rl = id >> 4;        // 0..31
            const int ch = id & 15;        // 0..15
            const int grow = m0 + (rl >> 4) * 64 + mi * 16 + (rl & 15);
            const short8_t v = *(const short8_t*)&St[rl * 136 + ch * 8];
            if (grow < M)
                *(short8_t*)&Y[(size_t)grow * DIM + n0 + ch * 8] = v;
        }
        __syncthreads();
    }
}

// ---------------- CSR build: histogram -> scan -> fill ----------------
__global__ __launch_bounds__(256) void count_dst(
    const int* __restrict__ dst, int E, int* __restrict__ cnt)
{
    const int e = blockIdx.x * blockDim.x + threadIdx.x;
    if (e < E) atomicAdd(&cnt[dst[e]], 1);
}

__global__ __launch_bounds__(1024) void scan_counts(
    const int* __restrict__ cnt, int N, int* __restrict__ rowptr,
    int* __restrict__ cursor)
{
    __shared__ int part[1024];
    const int t = threadIdx.x;
    const int chunk = (N + 1023) / 1024;
    const int lo = t * chunk;
    const int hi = min(lo + chunk, N);
    int s = 0;
    for (int i = lo; i < hi; i++) s += cnt[i];
    part[t] = s;
    __syncthreads();
    for (int off = 1; off < 1024; off <<= 1) {
        const int v = part[t];
        const int add = (t >= off) ? part[t - off] : 0;
        __syncthreads();
        part[t] = v + add;
        __syncthreads();
    }
    int run = (t == 0) ? 0 : part[t - 1];
    for (int i = lo; i < hi; i++) {
        const int c = cnt[i];
        rowptr[i] = run;
        cursor[i] = run;
        run += c;
    }
    if (t == 1023) rowptr[N] = part[1023];
}

__global__ __launch_bounds__(256) void fill_edges(
    const int* __restrict__ src, const int* __restrict__ dst,
    const int* __restrict__ et, int E, int* __restrict__ cursor,
    unsigned* __restrict__ ep)
{
    const int e = blockIdx.x * blockDim.x + threadIdx.x;
    if (e >= E) return;
    const int pos = atomicAdd(&cursor[dst[e]], 1);
    ep[pos] = (unsigned)src[e] | ((unsigned)et[e] << 16);
}

// -------- aggregate: gather + sum, 2 edges/wave, plane layout, no atomics ---
template <typename OT>
__global__ __launch_bounds__(256) void aggregate2(
    const unsigned short* __restrict__ yall,   // [R][M][256]
    const unsigned* __restrict__ ep, const int* __restrict__ rowptr,
    OT* __restrict__ out, int M)
{
    const int lane = threadIdx.x & 63;
    const int half = lane >> 5;     // which edge of the pair
    const int cl = lane & 31;       // 8-short chunk within message row
    const int wv = (blockIdx.x * blockDim.x + threadIdx.x) >> 6;
    const int nw = (gridDim.x * blockDim.x) >> 6;
    const size_t plane = (size_t)M * DIM;

    for (int d = wv; d < M; d += nw) {
        const int beg = rowptr[d], end = rowptr[d + 1];
        float acc[8];
#pragma unroll
        for (int j = 0; j < 8; j++) acc[j] = 0.f;

        for (int c0 = beg; c0 < end; c0 += 64) {
            const int n = min(64, end - c0);
            const unsigned myep = (c0 + lane < end) ? ep[c0 + lane] : 0u;
            for (int i = 0; i < n; i += 2) {
                const int idx = i + half;
                const unsigned p = __shfl(myep, idx);
                if (idx < n) {
                    const unsigned short* yr = yall + (size_t)(p >> 16) * plane +
                                               (size_t)(p & 0xFFFFu) * DIM + cl * 8;
                    const short8_t u = *(const short8_t*)yr;
#pragma unroll
                    for (int j = 0; j < 8; j++)
                        acc[j] += bf2f((unsigned short)u[j]);
                }
            }
        }
        // fold the two halves: lane l (<32) adds lane l+32's accumulator
        float o[8];
#pragma unroll
        for (int j = 0; j < 8; j++)
            o[j] = acc[j] + __shfl(acc[j], (lane + 32) & 63);
        if (lane < 32) {
            OT* dp = out + (size_t)d * DIM + cl * 8;
            if (sizeof(OT) == 4) {
                *(float4*)((float*)dp) = make_float4(o[0], o[1], o[2], o[3]);
                *(float4*)((float*)dp + 4) = make_float4(o[4], o[5], o[6], o[7]);
            } else {
                short8_t v;
#pragma unroll
                for (int j = 0; j < 8; j++) v[j] = (short)f2bf(o[j]);
                *(short8_t*)((unsigned short*)dp) = v;
            }
        }
    }
}

// ---------------- fallback: fp32 vector GEMM + atomic scatter ----------------
__global__ __launch_bounds__(256) void gemm_bias_relu_f32(
    const float* __restrict__ A, const float* __restrict__ B,
    const float* __restrict__ bias, float* __restrict__ Y, int M)
{
    __shared__ float Asf[16][132];
    __shared__ float Bsf[16][128];
    const int t = threadIdx.x;
    const int tx = t & 15, ty = t >> 4;
    const int row0 = blockIdx.x * 128, col0 = blockIdx.y * 128;
    float acc[8][8];
#pragma unroll
    for (int i = 0; i < 8; i++)
#pragma unroll
        for (int j = 0; j < 8; j++) acc[i][j] = 0.f;
    const int arow = t >> 2, akseg = (t & 3) * 4;
    const int bk0 = t >> 5, bcol = (t & 31) * 4;
    for (int k0 = 0; k0 < DIM; k0 += 16) {
#pragma unroll
        for (int h = 0; h < 2; h++) {
            const int row = row0 + arow + h * 64;
            float4 av = (row < M) ? *(const float4*)(A + (size_t)row * DIM + k0 + akseg)
                                  : make_float4(0, 0, 0, 0);
            Asf[akseg + 0][arow + h * 64] = av.x;
            Asf[akseg + 1][arow + h * 64] = av.y;
            Asf[akseg + 2][arow + h * 64] = av.z;
            Asf[akseg + 3][arow + h * 64] = av.w;
        }
#pragma unroll
        for (int h = 0; h < 2; h++) {
            const int krow = bk0 + h * 8;
            *(float4*)&Bsf[krow][bcol] =
                *(const float4*)(B + (size_t)(k0 + krow) * DIM + col0 + bcol);
        }
        __syncthreads();
#pragma unroll
        for (int k = 0; k < 16; k++) {
            float a[8], b[8];
            *(float4*)&a[0] = *(const float4*)&Asf[k][ty * 4];
            *(float4*)&a[4] = *(const float4*)&Asf[k][64 + ty * 4];
            *(float4*)&b[0] = *(const float4*)&Bsf[k][tx * 4];
            *(float4*)&b[4] = *(const float4*)&Bsf[k][64 + tx * 4];
#pragma unroll
            for (int i = 0; i < 8; i++)
#pragma unroll
                for (int j = 0; j < 8; j++) acc[i][j] = fmaf(a[i], b[j], acc[i][j]);
        }
        __syncthreads();
    }
#pragma unroll
    for (int im = 0; im < 2; im++)
#pragma unroll
        for (int i = 0; i < 4; i++) {
            const int row = row0 + im * 64 + ty * 4 + i;
            if (row >= M) continue;
#pragma unroll
            for (int jm = 0; jm < 2; jm++) {
                const int col = col0 + jm * 64 + tx * 4;
                const float4 bb = *(const float4*)(bias + col);
                float4 o;
                o.x = fmaxf(acc[im * 4 + i][jm * 4 + 0] + bb.x, 0.f);
                o.y = fmaxf(acc[im * 4 + i][jm * 4 + 1] + bb.y, 0.f);
                o.z = fmaxf(acc[im * 4 + i][jm * 4 + 2] + bb.z, 0.f);
                o.w = fmaxf(acc[im * 4 + i][jm * 4 + 3] + bb.w, 0.f);
                *(float4*)(Y + (size_t)row * DIM + col) = o;
            }
        }
}

__global__ __launch_bounds__(256) void scatter_rel(
    const float* __restrict__ y, const int* __restrict__ src,
    const int* __restrict__ dst, const int* __restrict__ et,
    int rel, float* __restrict__ out, int n_edges)
{
    const int lane = threadIdx.x & 63;
    const int wave = (blockIdx.x * blockDim.x + threadIdx.x) >> 6;
    const int nwaves = (gridDim.x * blockDim.x) >> 6;
    for (int e = wave; e < n_edges; e += nwaves) {
        if (et[e] != rel) continue;
        const float4 v = *(const float4*)(y + (size_t)src[e] * DIM + lane * 4);
        float* o = out + (size_t)dst[e] * DIM + lane * 4;
        atomicAdd(o + 0, v.x);
        atomicAdd(o + 1, v.y);
        atomicAdd(o + 2, v.z);
        atomicAdd(o + 3, v.w);
    }
}

static inline size_t align16(size_t x) { return (x + 15) & ~(size_t)15; }

extern "C" void kernel_launch(void* const* d_in, const int* in_sizes, int n_in,
                              void* d_out, int out_size, void* d_ws, size_t ws_size,
                              hipStream_t stream)
{
    const float* x  = (const float*)d_in[0];
    const float* W0 = (const float*)d_in[1];
    const float* b0 = (const float*)d_in[2];
    const float* W1 = (const float*)d_in[3];
    const float* b1 = (const float*)d_in[4];
    const int* eidx = (const int*)d_in[5];
    const int* etyp = (const int*)d_in[6];

    const int M = in_sizes[0] / DIM;   // 50000
    const int E = in_sizes[6];         // 800000
    const int* src = eidx;
    const int* dst = eidx + E;
    float* out = (float*)d_out;

    const size_t plane = (size_t)M * DIM;
    const size_t wbytes = (size_t)N_REL * DIM * DIM * 2;

    const size_t need = align16(plane * 2)              // h1b
                      + align16(plane * 2)              // xb
                      + 2 * align16(wbytes)             // Wt0b, Wt1b
                      + align16((size_t)(M + 1) * 4)    // rowptr
                      + 2 * align16((size_t)M * 4)      // cnt, cursor
                      + align16((size_t)E * 4)          // ep
                      + align16((size_t)N_REL * plane * 2);  // yall

    if (M < 65536 && ws_size >= need) {
        char* ws = (char*)d_ws;
        size_t off = 0;
        unsigned short* h1b  = (unsigned short*)(ws + off); off = align16(off + plane * 2);
        unsigned short* xb   = (unsigned short*)(ws + off); off = align16(off + plane * 2);
        unsigned short* Wt0b = (unsigned short*)(ws + off); off = align16(off + wbytes);
        unsigned short* Wt1b = (unsigned short*)(ws + off); off = align16(off + wbytes);
        int* rowptr = (int*)(ws + off); off = align16(off + (size_t)(M + 1) * 4);
        int* cnt    = (int*)(ws + off); off = align16(off + (size_t)M * 4);
        int* cursor = (int*)(ws + off); off = align16(off + (size_t)M * 4);
        unsigned* ep = (unsigned*)(ws + off); off = align16(off + (size_t)E * 4);
        unsigned short* yall = (unsigned short*)(ws + off);

        // CSR build (shared by both layers)
        hipMemsetAsync(cnt, 0, (size_t)M * 4, stream);
        count_dst<<<(E + 255) / 256, 256, 0, stream>>>(dst, E, cnt);
        scan_counts<<<1, 1024, 0, stream>>>(cnt, M, rowptr, cursor);
        fill_edges<<<(E + 255) / 256, 256, 0, stream>>>(src, dst, etyp, E, cursor, ep);

        // prep: casts / transposes
        cast_f32_bf16<<<(int)((plane / 4 + 255) / 256), 256, 0, stream>>>(
            x, xb, (int)(plane / 4));
        transpose_cast_w<<<dim3(8, 8, N_REL), dim3(32, 8), 0, stream>>>(W0, Wt0b);
        transpose_cast_w<<<dim3(8, 8, N_REL), dim3(32, 8), 0, stream>>>(W1, Wt1b);

        const dim3 gblk(256), ggrid((M + 127) / 128, DIM / 128, N_REL);
        const int agrid = (int)(((size_t)M * 64 + 255) / 256); // 1 wave/dst

        // layer 1
        gemm_mfma_bias_relu<<<ggrid, gblk, 0, stream>>>(xb, Wt0b, b0, yall, M);
        aggregate2<unsigned short><<<agrid, 256, 0, stream>>>(yall, ep, rowptr, h1b, M);
        // layer 2
        gemm_mfma_bias_relu<<<ggrid, gblk, 0, stream>>>(h1b, Wt1b, b1, yall, M);
        aggregate2<float><<<agrid, 256, 0, stream>>>(yall, ep, rowptr, out, M);
    } else {
        // fallback: fp32 per-relation GEMM + atomic scatter
        float* h1 = (float*)d_ws;
        float* y  = (float*)d_ws + plane;
        const dim3 gblk(256), ggrid2((M + 127) / 128, DIM / 128);
        hipMemsetAsync(h1, 0, plane * 4, stream);
        for (int r = 0; r < N_REL; r++) {
            gemm_bias_relu_f32<<<ggrid2, gblk, 0, stream>>>(
                x, W0 + (size_t)r * DIM * DIM, b0, y, M);
            scatter_rel<<<1024, 256, 0, stream>>>(y, src, dst, etyp, r, h1, E);
        }
        hipMemsetAsync(out, 0, plane * 4, stream);
        for (int r = 0; r < N_REL; r++) {
            gemm_bias_relu_f32<<<ggrid2, gblk, 0, stream>>>(
                h1, W1 + (size_t)r * DIM * DIM, b1, y, M);
            scatter_rel<<<1024, 256, 0, stream>>>(y, src, dst, etyp, r, out, E);
        }
    }
}

// Round 6
// 716.766 us; speedup vs baseline: 2.5514x; 2.5514x over previous
//
#include <hip/hip_runtime.h>

#define DIM 256
#define N_REL 8

typedef __attribute__((ext_vector_type(8))) short short8_t;
typedef __attribute__((ext_vector_type(4))) float float4_t;

// ---------------- bf16 helpers (manual, RNE) ----------------
__device__ inline unsigned short f2bf(float f) {
    unsigned u = __float_as_uint(f);
    u += 0x7FFFu + ((u >> 16) & 1u);
    return (unsigned short)(u >> 16);
}
__device__ inline float bf2f(unsigned short h) {
    return __uint_as_float(((unsigned)h) << 16);
}

// ---------------- cast / transpose prep kernels ----------------
__global__ __launch_bounds__(256) void cast_f32_bf16(
    const float* __restrict__ in, unsigned short* __restrict__ out, int n4)
{
    const int i = blockIdx.x * blockDim.x + threadIdx.x;
    if (i >= n4) return;
    const float4 v = ((const float4*)in)[i];
    ushort4 o;
    o.x = f2bf(v.x); o.y = f2bf(v.y); o.z = f2bf(v.z); o.w = f2bf(v.w);
    ((ushort4*)out)[i] = o;
}

// W[rel][in][out] f32  ->  Wt[rel][out][in] bf16
__global__ __launch_bounds__(256) void transpose_cast_w(
    const float* __restrict__ W, unsigned short* __restrict__ Wt)
{
    __shared__ float tile[32][33];
    const int rel = blockIdx.z;
    const int i0 = blockIdx.x * 32, o0 = blockIdx.y * 32;
    const int tx = threadIdx.x, ty = threadIdx.y;   // (32, 8)
    const float* Wr = W + (size_t)rel * DIM * DIM;
    unsigned short* Wtr = Wt + (size_t)rel * DIM * DIM;
#pragma unroll
    for (int j = 0; j < 4; j++)
        tile[ty + 8 * j][tx] = Wr[(size_t)(i0 + ty + 8 * j) * DIM + o0 + tx];
    __syncthreads();
#pragma unroll
    for (int j = 0; j < 4; j++)
        Wtr[(size_t)(o0 + ty + 8 * j) * DIM + i0 + tx] = f2bf(tile[tx][ty + 8 * j]);
}

// ---------------------------------------------------------------------------
// Yall[rel][M][256] = relu(Xb @ W[rel] + bias) in bf16.
// Tile 128x128, BK=32, 4 waves of 64x64 (4x4 mfma_f32_16x16x32_bf16).
// Epilogue staged through LDS -> full 256B coalesced row-segment stores.
// NOTE: epilogue mi-loop MUST be fully unrolled: a runtime index into acc[]
// demotes the accumulator to scratch (R4/R5: 3.7 GB WRITE_SIZE, VGPR 88->64).
// ---------------------------------------------------------------------------
__global__ __launch_bounds__(256) void gemm_mfma_bias_relu(
    const unsigned short* __restrict__ Xb,    // [M][256]
    const unsigned short* __restrict__ Wtb,   // [R][256out][256in]
    const float* __restrict__ bias,           // [256]
    unsigned short* __restrict__ Yall, int M)
{
    __shared__ __align__(16) short smem[10240]; // As 5120 | Bs 5120 shorts
    short* As = smem;
    short* Bs = smem + 5120;

    const int m0 = blockIdx.x * 128;
    const int n0 = blockIdx.y * 128;
    const int rel = blockIdx.z;

    const unsigned short* Wt = Wtb + (size_t)rel * DIM * DIM;
    unsigned short* Y = Yall + (size_t)rel * M * DIM;

    const int t = threadIdx.x;
    const int lane = t & 63;
    const int w = t >> 6;
    const int wr = w & 1, wc = w >> 1;
    const int r = lane & 15, q = lane >> 4;

    const int rowA0 = t >> 2;     // 0..63 (+64 second half)
    const int segA0 = t & 3;      // 16B segment within 64B row

    float4_t acc[4][4];
#pragma unroll
    for (int i = 0; i < 4; i++)
#pragma unroll
        for (int j = 0; j < 4; j++) {
            float4_t z = {0.f, 0.f, 0.f, 0.f};
            acc[i][j] = z;
        }

    short8_t ra[2], rb[2];
    const short8_t zero8 = {0, 0, 0, 0, 0, 0, 0, 0};

#define LOAD_TILES(ks)                                                            \
    {                                                                             \
        const int k0_ = (ks) * 32;                                                \
        _Pragma("unroll")                                                         \
        for (int h = 0; h < 2; h++) {                                             \
            const int row_ = rowA0 + h * 64;                                      \
            const int m_ = m0 + row_;                                             \
            if (m_ < M)                                                           \
                ra[h] = *(const short8_t*)(Xb + (size_t)m_ * DIM + k0_ + segA0 * 8); \
            else                                                                  \
                ra[h] = zero8;                                                    \
            rb[h] = *(const short8_t*)(Wt + (size_t)(n0 + row_) * DIM + k0_ + segA0 * 8); \
        }                                                                         \
    }

    LOAD_TILES(0);
#pragma unroll 1
    for (int ks = 0; ks < 8; ks++) {
#pragma unroll
        for (int h = 0; h < 2; h++) {
            const int row_ = rowA0 + h * 64;
            *(short8_t*)&As[row_ * 40 + segA0 * 8] = ra[h];
            *(short8_t*)&Bs[row_ * 40 + segA0 * 8] = rb[h];
        }
        __syncthreads();
        if (ks < 7) LOAD_TILES(ks + 1);

        short8_t af[4], bf[4];
#pragma unroll
        for (int mi = 0; mi < 4; mi++)
            af[mi] = *(const short8_t*)&As[(wr * 64 + mi * 16 + r) * 40 + q * 8];
#pragma unroll
        for (int ni = 0; ni < 4; ni++)
            bf[ni] = *(const short8_t*)&Bs[(wc * 64 + ni * 16 + r) * 40 + q * 8];
#pragma unroll
        for (int mi = 0; mi < 4; mi++)
#pragma unroll
            for (int ni = 0; ni < 4; ni++)
                acc[mi][ni] = __builtin_amdgcn_mfma_f32_16x16x32_bf16(
                    af[mi], bf[ni], acc[mi][ni], 0, 0, 0);
        __syncthreads();
    }
#undef LOAD_TILES

    // -------- epilogue: bias+relu, LDS-staged coalesced bf16 stores --------
    short* St = smem;   // 32*136 = 4352 shorts, aliases As/Bs (K-loop done)

    float bv[4];
#pragma unroll
    for (int ni = 0; ni < 4; ni++)
        bv[ni] = bias[n0 + wc * 64 + ni * 16 + r];

#pragma unroll
    for (int mi = 0; mi < 4; mi++) {
#pragma unroll
        for (int ni = 0; ni < 4; ni++) {
#pragma unroll
            for (int e = 0; e < 4; e++) {
                const int rl = wr * 16 + q * 4 + e;
                const int col = wc * 64 + ni * 16 + r;
                St[rl * 136 + col] = f2bf(fmaxf(acc[mi][ni][e] + bv[ni], 0.f));
            }
        }
        __syncthreads();
        // readout: 512 chunks of 8 shorts (16B); each thread stores 2
#pragma unroll
        for (int j = 0; j < 2; j++) {
            const int id = t + 256 * j;
            const int rl = id >> 4;        // 0..31
            const int ch = id & 15;        // 0..15
            const int grow = m0 + (rl >> 4) * 64 + mi * 16 + (rl & 15);
            const short8_t v = *(const short8_t*)&St[rl * 136 + ch * 8];
            if (grow < M)
                *(short8_t*)&Y[(size_t)grow * DIM + n0 + ch * 8] = v;
        }
        __syncthreads();
    }
}

// ---------------- CSR build: histogram -> scan -> fill ----------------
__global__ __launch_bounds__(256) void count_dst(
    const int* __restrict__ dst, int E, int* __restrict__ cnt)
{
    const int e = blockIdx.x * blockDim.x + threadIdx.x;
    if (e < E) atomicAdd(&cnt[dst[e]], 1);
}

__global__ __launch_bounds__(1024) void scan_counts(
    const int* __restrict__ cnt, int N, int* __restrict__ rowptr,
    int* __restrict__ cursor)
{
    __shared__ int part[1024];
    const int t = threadIdx.x;
    const int chunk = (N + 1023) / 1024;
    const int lo = t * chunk;
    const int hi = min(lo + chunk, N);
    int s = 0;
    for (int i = lo; i < hi; i++) s += cnt[i];
    part[t] = s;
    __syncthreads();
    for (int off = 1; off < 1024; off <<= 1) {
        const int v = part[t];
        const int add = (t >= off) ? part[t - off] : 0;
        __syncthreads();
        part[t] = v + add;
        __syncthreads();
    }
    int run = (t == 0) ? 0 : part[t - 1];
    for (int i = lo; i < hi; i++) {
        const int c = cnt[i];
        rowptr[i] = run;
        cursor[i] = run;
        run += c;
    }
    if (t == 1023) rowptr[N] = part[1023];
}

__global__ __launch_bounds__(256) void fill_edges(
    const int* __restrict__ src, const int* __restrict__ dst,
    const int* __restrict__ et, int E, int* __restrict__ cursor,
    unsigned* __restrict__ ep)
{
    const int e = blockIdx.x * blockDim.x + threadIdx.x;
    if (e >= E) return;
    const int pos = atomicAdd(&cursor[dst[e]], 1);
    ep[pos] = (unsigned)src[e] | ((unsigned)et[e] << 16);
}

// -------- aggregate: gather + sum, 2 edges/wave, plane layout, no atomics ---
template <typename OT>
__global__ __launch_bounds__(256) void aggregate2(
    const unsigned short* __restrict__ yall,   // [R][M][256]
    const unsigned* __restrict__ ep, const int* __restrict__ rowptr,
    OT* __restrict__ out, int M)
{
    const int lane = threadIdx.x & 63;
    const int half = lane >> 5;     // which edge of the pair
    const int cl = lane & 31;       // 8-short chunk within message row
    const int wv = (blockIdx.x * blockDim.x + threadIdx.x) >> 6;
    const int nw = (gridDim.x * blockDim.x) >> 6;
    const size_t plane = (size_t)M * DIM;

    for (int d = wv; d < M; d += nw) {
        const int beg = rowptr[d], end = rowptr[d + 1];
        float acc[8];
#pragma unroll
        for (int j = 0; j < 8; j++) acc[j] = 0.f;

        for (int c0 = beg; c0 < end; c0 += 64) {
            const int n = min(64, end - c0);
            const unsigned myep = (c0 + lane < end) ? ep[c0 + lane] : 0u;
            for (int i = 0; i < n; i += 2) {
                const int idx = i + half;
                const unsigned p = __shfl(myep, idx);
                if (idx < n) {
                    const unsigned short* yr = yall + (size_t)(p >> 16) * plane +
                                               (size_t)(p & 0xFFFFu) * DIM + cl * 8;
                    const short8_t u = *(const short8_t*)yr;
#pragma unroll
                    for (int j = 0; j < 8; j++)
                        acc[j] += bf2f((unsigned short)u[j]);
                }
            }
        }
        // fold the two halves: lane l (<32) adds lane l+32's accumulator
        float o[8];
#pragma unroll
        for (int j = 0; j < 8; j++)
            o[j] = acc[j] + __shfl(acc[j], (lane + 32) & 63);
        if (lane < 32) {
            OT* dp = out + (size_t)d * DIM + cl * 8;
            if (sizeof(OT) == 4) {
                *(float4*)((float*)dp) = make_float4(o[0], o[1], o[2], o[3]);
                *(float4*)((float*)dp + 4) = make_float4(o[4], o[5], o[6], o[7]);
            } else {
                short8_t v;
#pragma unroll
                for (int j = 0; j < 8; j++) v[j] = (short)f2bf(o[j]);
                *(short8_t*)((unsigned short*)dp) = v;
            }
        }
    }
}

// ---------------- fallback: fp32 vector GEMM + atomic scatter ----------------
__global__ __launch_bounds__(256) void gemm_bias_relu_f32(
    const float* __restrict__ A, const float* __restrict__ B,
    const float* __restrict__ bias, float* __restrict__ Y, int M)
{
    __shared__ float Asf[16][132];
    __shared__ float Bsf[16][128];
    const int t = threadIdx.x;
    const int tx = t & 15, ty = t >> 4;
    const int row0 = blockIdx.x * 128, col0 = blockIdx.y * 128;
    float acc[8][8];
#pragma unroll
    for (int i = 0; i < 8; i++)
#pragma unroll
        for (int j = 0; j < 8; j++) acc[i][j] = 0.f;
    const int arow = t >> 2, akseg = (t & 3) * 4;
    const int bk0 = t >> 5, bcol = (t & 31) * 4;
    for (int k0 = 0; k0 < DIM; k0 += 16) {
#pragma unroll
        for (int h = 0; h < 2; h++) {
            const int row = row0 + arow + h * 64;
            float4 av = (row < M) ? *(const float4*)(A + (size_t)row * DIM + k0 + akseg)
                                  : make_float4(0, 0, 0, 0);
            Asf[akseg + 0][arow + h * 64] = av.x;
            Asf[akseg + 1][arow + h * 64] = av.y;
            Asf[akseg + 2][arow + h * 64] = av.z;
            Asf[akseg + 3][arow + h * 64] = av.w;
        }
#pragma unroll
        for (int h = 0; h < 2; h++) {
            const int krow = bk0 + h * 8;
            *(float4*)&Bsf[krow][bcol] =
                *(const float4*)(B + (size_t)(k0 + krow) * DIM + col0 + bcol);
        }
        __syncthreads();
#pragma unroll
        for (int k = 0; k < 16; k++) {
            float a[8], b[8];
            *(float4*)&a[0] = *(const float4*)&Asf[k][ty * 4];
            *(float4*)&a[4] = *(const float4*)&Asf[k][64 + ty * 4];
            *(float4*)&b[0] = *(const float4*)&Bsf[k][tx * 4];
            *(float4*)&b[4] = *(const float4*)&Bsf[k][64 + tx * 4];
#pragma unroll
            for (int i = 0; i < 8; i++)
#pragma unroll
                for (int j = 0; j < 8; j++) acc[i][j] = fmaf(a[i], b[j], acc[i][j]);
        }
        __syncthreads();
    }
#pragma unroll
    for (int im = 0; im < 2; im++)
#pragma unroll
        for (int i = 0; i < 4; i++) {
            const int row = row0 + im * 64 + ty * 4 + i;
            if (row >= M) continue;
#pragma unroll
            for (int jm = 0; jm < 2; jm++) {
                const int col = col0 + jm * 64 + tx * 4;
                const float4 bb = *(const float4*)(bias + col);
                float4 o;
                o.x = fmaxf(acc[im * 4 + i][jm * 4 + 0] + bb.x, 0.f);
                o.y = fmaxf(acc[im * 4 + i][jm * 4 + 1] + bb.y, 0.f);
                o.z = fmaxf(acc[im * 4 + i][jm * 4 + 2] + bb.z, 0.f);
                o.w = fmaxf(acc[im * 4 + i][jm * 4 + 3] + bb.w, 0.f);
                *(float4*)(Y + (size_t)row * DIM + col) = o;
            }
        }
}

__global__ __launch_bounds__(256) void scatter_rel(
    const float* __restrict__ y, const int* __restrict__ src,
    const int* __restrict__ dst, const int* __restrict__ et,
    int rel, float* __restrict__ out, int n_edges)
{
    const int lane = threadIdx.x & 63;
    const int wave = (blockIdx.x * blockDim.x + threadIdx.x) >> 6;
    const int nwaves = (gridDim.x * blockDim.x) >> 6;
    for (int e = wave; e < n_edges; e += nwaves) {
        if (et[e] != rel) continue;
        const float4 v = *(const float4*)(y + (size_t)src[e] * DIM + lane * 4);
        float* o = out + (size_t)dst[e] * DIM + lane * 4;
        atomicAdd(o + 0, v.x);
        atomicAdd(o + 1, v.y);
        atomicAdd(o + 2, v.z);
        atomicAdd(o + 3, v.w);
    }
}

static inline size_t align16(size_t x) { return (x + 15) & ~(size_t)15; }

extern "C" void kernel_launch(void* const* d_in, const int* in_sizes, int n_in,
                              void* d_out, int out_size, void* d_ws, size_t ws_size,
                              hipStream_t stream)
{
    const float* x  = (const float*)d_in[0];
    const float* W0 = (const float*)d_in[1];
    const float* b0 = (const float*)d_in[2];
    const float* W1 = (const float*)d_in[3];
    const float* b1 = (const float*)d_in[4];
    const int* eidx = (const int*)d_in[5];
    const int* etyp = (const int*)d_in[6];

    const int M = in_sizes[0] / DIM;   // 50000
    const int E = in_sizes[6];         // 800000
    const int* src = eidx;
    const int* dst = eidx + E;
    float* out = (float*)d_out;

    const size_t plane = (size_t)M * DIM;
    const size_t wbytes = (size_t)N_REL * DIM * DIM * 2;

    const size_t need = align16(plane * 2)              // h1b
                      + align16(plane * 2)              // xb
                      + 2 * align16(wbytes)             // Wt0b, Wt1b
                      + align16((size_t)(M + 1) * 4)    // rowptr
                      + 2 * align16((size_t)M * 4)      // cnt, cursor
                      + align16((size_t)E * 4)          // ep
                      + align16((size_t)N_REL * plane * 2);  // yall

    if (M < 65536 && ws_size >= need) {
        char* ws = (char*)d_ws;
        size_t off = 0;
        unsigned short* h1b  = (unsigned short*)(ws + off); off = align16(off + plane * 2);
        unsigned short* xb   = (unsigned short*)(ws + off); off = align16(off + plane * 2);
        unsigned short* Wt0b = (unsigned short*)(ws + off); off = align16(off + wbytes);
        unsigned short* Wt1b = (unsigned short*)(ws + off); off = align16(off + wbytes);
        int* rowptr = (int*)(ws + off); off = align16(off + (size_t)(M + 1) * 4);
        int* cnt    = (int*)(ws + off); off = align16(off + (size_t)M * 4);
        int* cursor = (int*)(ws + off); off = align16(off + (size_t)M * 4);
        unsigned* ep = (unsigned*)(ws + off); off = align16(off + (size_t)E * 4);
        unsigned short* yall = (unsigned short*)(ws + off);

        // CSR build (shared by both layers)
        hipMemsetAsync(cnt, 0, (size_t)M * 4, stream);
        count_dst<<<(E + 255) / 256, 256, 0, stream>>>(dst, E, cnt);
        scan_counts<<<1, 1024, 0, stream>>>(cnt, M, rowptr, cursor);
        fill_edges<<<(E + 255) / 256, 256, 0, stream>>>(src, dst, etyp, E, cursor, ep);

        // prep: casts / transposes
        cast_f32_bf16<<<(int)((plane / 4 + 255) / 256), 256, 0, stream>>>(
            x, xb, (int)(plane / 4));
        transpose_cast_w<<<dim3(8, 8, N_REL), dim3(32, 8), 0, stream>>>(W0, Wt0b);
        transpose_cast_w<<<dim3(8, 8, N_REL), dim3(32, 8), 0, stream>>>(W1, Wt1b);

        const dim3 gblk(256), ggrid((M + 127) / 128, DIM / 128, N_REL);
        const int agrid = (int)(((size_t)M * 64 + 255) / 256); // 1 wave/dst

        // layer 1
        gemm_mfma_bias_relu<<<ggrid, gblk, 0, stream>>>(xb, Wt0b, b0, yall, M);
        aggregate2<unsigned short><<<agrid, 256, 0, stream>>>(yall, ep, rowptr, h1b, M);
        // layer 2
        gemm_mfma_bias_relu<<<ggrid, gblk, 0, stream>>>(h1b, Wt1b, b1, yall, M);
        aggregate2<float><<<agrid, 256, 0, stream>>>(yall, ep, rowptr, out, M);
    } else {
        // fallback: fp32 per-relation GEMM + atomic scatter
        float* h1 = (float*)d_ws;
        float* y  = (float*)d_ws + plane;
        const dim3 gblk(256), ggrid2((M + 127) / 128, DIM / 128);
        hipMemsetAsync(h1, 0, plane * 4, stream);
        for (int r = 0; r < N_REL; r++) {
            gemm_bias_relu_f32<<<ggrid2, gblk, 0, stream>>>(
                x, W0 + (size_t)r * DIM * DIM, b0, y, M);
            scatter_rel<<<1024, 256, 0, stream>>>(y, src, dst, etyp, r, h1, E);
        }
        hipMemsetAsync(out, 0, plane * 4, stream);
        for (int r = 0; r < N_REL; r++) {
            gemm_bias_relu_f32<<<ggrid2, gblk, 0, stream>>>(
                h1, W1 + (size_t)r * DIM * DIM, b1, y, M);
            scatter_rel<<<1024, 256, 0, stream>>>(y, src, dst, etyp, r, out, E);
        }
    }
}

// Round 7
// 645.883 us; speedup vs baseline: 2.8314x; 1.1097x over previous
//
#include <hip/hip_runtime.h>

#define DIM 256
#define N_REL 8

typedef __attribute__((ext_vector_type(8))) short short8_t;
typedef __attribute__((ext_vector_type(4))) float float4_t;

// ---------------- bf16 helpers (manual, RNE) ----------------
__device__ inline unsigned short f2bf(float f) {
    unsigned u = __float_as_uint(f);
    u += 0x7FFFu + ((u >> 16) & 1u);
    return (unsigned short)(u >> 16);
}
__device__ inline float bf2f(unsigned short h) {
    return __uint_as_float(((unsigned)h) << 16);
}

// ---------------- cast / transpose prep kernels ----------------
__global__ __launch_bounds__(256) void cast_f32_bf16(
    const float* __restrict__ in, unsigned short* __restrict__ out, int n4)
{
    const int i = blockIdx.x * blockDim.x + threadIdx.x;
    if (i >= n4) return;
    const float4 v = ((const float4*)in)[i];
    ushort4 o;
    o.x = f2bf(v.x); o.y = f2bf(v.y); o.z = f2bf(v.z); o.w = f2bf(v.w);
    ((ushort4*)out)[i] = o;
}

// W[rel][in][out] f32  ->  Wt[rel][out][in] bf16
__global__ __launch_bounds__(256) void transpose_cast_w(
    const float* __restrict__ W, unsigned short* __restrict__ Wt)
{
    __shared__ float tile[32][33];
    const int rel = blockIdx.z;
    const int i0 = blockIdx.x * 32, o0 = blockIdx.y * 32;
    const int tx = threadIdx.x, ty = threadIdx.y;   // (32, 8)
    const float* Wr = W + (size_t)rel * DIM * DIM;
    unsigned short* Wtr = Wt + (size_t)rel * DIM * DIM;
#pragma unroll
    for (int j = 0; j < 4; j++)
        tile[ty + 8 * j][tx] = Wr[(size_t)(i0 + ty + 8 * j) * DIM + o0 + tx];
    __syncthreads();
#pragma unroll
    for (int j = 0; j < 4; j++)
        Wtr[(size_t)(o0 + ty + 8 * j) * DIM + i0 + tx] = f2bf(tile[tx][ty + 8 * j]);
}

// ---------------------------------------------------------------------------
// Yall[rel][M][256] = relu(Xb @ W[rel] + bias) in bf16.
// Tile 128x128, BK=32, 4 waves of 64x64 (4x4 mfma_f32_16x16x32_bf16).
// 1-D grid, octet swizzle: row-tile rt = (L>>7)*8 | (L&7) pins each rt to one
// XCD across all 16 (ntile, rel) combos -> A-tile fetched once per XCD
// (R6: FETCH 214MB = 8x full A; expect ~35MB).
// Epilogue staged through LDS -> full 256B coalesced row-segment stores.
// NOTE: epilogue mi-loop MUST be fully unrolled: a runtime index into acc[]
// demotes the accumulator to scratch (R4/R5: 3.7 GB WRITE_SIZE, VGPR 88->64).
// ---------------------------------------------------------------------------
__global__ __launch_bounds__(256) void gemm_mfma_bias_relu(
    const unsigned short* __restrict__ Xb,    // [M][256]
    const unsigned short* __restrict__ Wtb,   // [R][256out][256in]
    const float* __restrict__ bias,           // [256]
    unsigned short* __restrict__ Yall, int M, int Rtiles)
{
    __shared__ __align__(16) short smem[10240]; // As 5120 | Bs 5120 shorts
    short* As = smem;
    short* Bs = smem + 5120;

    const unsigned L = blockIdx.x;
    const int xcd = L & 7;
    const unsigned g = L >> 3;
    const int combo = g & 15;                 // (ntile, rel)
    const int rt = (int)((g >> 4) << 3) | xcd;
    if (rt >= Rtiles) return;
    const int m0 = rt * 128;
    const int n0 = (combo & 1) * 128;
    const int rel = combo >> 1;

    const unsigned short* Wt = Wtb + (size_t)rel * DIM * DIM;
    unsigned short* Y = Yall + (size_t)rel * M * DIM;

    const int t = threadIdx.x;
    const int lane = t & 63;
    const int w = t >> 6;
    const int wr = w & 1, wc = w >> 1;
    const int r = lane & 15, q = lane >> 4;

    const int rowA0 = t >> 2;     // 0..63 (+64 second half)
    const int segA0 = t & 3;      // 16B segment within 64B row

    float4_t acc[4][4];
#pragma unroll
    for (int i = 0; i < 4; i++)
#pragma unroll
        for (int j = 0; j < 4; j++) {
            float4_t z = {0.f, 0.f, 0.f, 0.f};
            acc[i][j] = z;
        }

    short8_t ra[2], rb[2];
    const short8_t zero8 = {0, 0, 0, 0, 0, 0, 0, 0};

#define LOAD_TILES(ks)                                                            \
    {                                                                             \
        const int k0_ = (ks) * 32;                                                \
        _Pragma("unroll")                                                         \
        for (int h = 0; h < 2; h++) {                                             \
            const int row_ = rowA0 + h * 64;                                      \
            const int m_ = m0 + row_;                                             \
            if (m_ < M)                                                           \
                ra[h] = *(const short8_t*)(Xb + (size_t)m_ * DIM + k0_ + segA0 * 8); \
            else                                                                  \
                ra[h] = zero8;                                                    \
            rb[h] = *(const short8_t*)(Wt + (size_t)(n0 + row_) * DIM + k0_ + segA0 * 8); \
        }                                                                         \
    }

    LOAD_TILES(0);
#pragma unroll 1
    for (int ks = 0; ks < 8; ks++) {
#pragma unroll
        for (int h = 0; h < 2; h++) {
            const int row_ = rowA0 + h * 64;
            *(short8_t*)&As[row_ * 40 + segA0 * 8] = ra[h];
            *(short8_t*)&Bs[row_ * 40 + segA0 * 8] = rb[h];
        }
        __syncthreads();
        if (ks < 7) LOAD_TILES(ks + 1);

        short8_t af[4], bf[4];
#pragma unroll
        for (int mi = 0; mi < 4; mi++)
            af[mi] = *(const short8_t*)&As[(wr * 64 + mi * 16 + r) * 40 + q * 8];
#pragma unroll
        for (int ni = 0; ni < 4; ni++)
            bf[ni] = *(const short8_t*)&Bs[(wc * 64 + ni * 16 + r) * 40 + q * 8];
#pragma unroll
        for (int mi = 0; mi < 4; mi++)
#pragma unroll
            for (int ni = 0; ni < 4; ni++)
                acc[mi][ni] = __builtin_amdgcn_mfma_f32_16x16x32_bf16(
                    af[mi], bf[ni], acc[mi][ni], 0, 0, 0);
        __syncthreads();
    }
#undef LOAD_TILES

    // -------- epilogue: bias+relu, LDS-staged coalesced bf16 stores --------
    short* St = smem;   // 32*136 = 4352 shorts, aliases As/Bs (K-loop done)

    float bv[4];
#pragma unroll
    for (int ni = 0; ni < 4; ni++)
        bv[ni] = bias[n0 + wc * 64 + ni * 16 + r];

#pragma unroll
    for (int mi = 0; mi < 4; mi++) {
#pragma unroll
        for (int ni = 0; ni < 4; ni++) {
#pragma unroll
            for (int e = 0; e < 4; e++) {
                const int rl = wr * 16 + q * 4 + e;
                const int col = wc * 64 + ni * 16 + r;
                St[rl * 136 + col] = f2bf(fmaxf(acc[mi][ni][e] + bv[ni], 0.f));
            }
        }
        __syncthreads();
        // readout: 512 chunks of 8 shorts (16B); each thread stores 2
#pragma unroll
        for (int j = 0; j < 2; j++) {
            const int id = t + 256 * j;
            const int rl = id >> 4;        // 0..31
            const int ch = id & 15;        // 0..15
            const int grow = m0 + (rl >> 4) * 64 + mi * 16 + (rl & 15);
            const short8_t v = *(const short8_t*)&St[rl * 136 + ch * 8];
            if (grow < M)
                *(short8_t*)&Y[(size_t)grow * DIM + n0 + ch * 8] = v;
        }
        __syncthreads();
    }
}

// ---------------- CSR build: histogram -> scan -> fill ----------------
__global__ __launch_bounds__(256) void count_dst(
    const int* __restrict__ dst, int E, int* __restrict__ cnt)
{
    const int e = blockIdx.x * blockDim.x + threadIdx.x;
    if (e < E) atomicAdd(&cnt[dst[e]], 1);
}

__global__ __launch_bounds__(1024) void scan_counts(
    const int* __restrict__ cnt, int N, int* __restrict__ rowptr,
    int* __restrict__ cursor)
{
    __shared__ int part[1024];
    const int t = threadIdx.x;
    const int chunk = (N + 1023) / 1024;
    const int lo = t * chunk;
    const int hi = min(lo + chunk, N);
    int s = 0;
    for (int i = lo; i < hi; i++) s += cnt[i];
    part[t] = s;
    __syncthreads();
    for (int off = 1; off < 1024; off <<= 1) {
        const int v = part[t];
        const int add = (t >= off) ? part[t - off] : 0;
        __syncthreads();
        part[t] = v + add;
        __syncthreads();
    }
    int run = (t == 0) ? 0 : part[t - 1];
    for (int i = lo; i < hi; i++) {
        const int c = cnt[i];
        rowptr[i] = run;
        cursor[i] = run;
        run += c;
    }
    if (t == 1023) rowptr[N] = part[1023];
}

__global__ __launch_bounds__(256) void fill_edges(
    const int* __restrict__ src, const int* __restrict__ dst,
    const int* __restrict__ et, int E, int* __restrict__ cursor,
    unsigned* __restrict__ ep)
{
    const int e = blockIdx.x * blockDim.x + threadIdx.x;
    if (e >= E) return;
    const int pos = atomicAdd(&cursor[dst[e]], 1);
    ep[pos] = (unsigned)src[e] | ((unsigned)et[e] << 16);
}

// -------- aggregate: gather + sum, 2 edges/wave, unroll x2 for MLP ---------
template <typename OT>
__global__ __launch_bounds__(256) void aggregate4(
    const unsigned short* __restrict__ yall,   // [R][M][256]
    const unsigned* __restrict__ ep, const int* __restrict__ rowptr,
    OT* __restrict__ out, int M)
{
    const int lane = threadIdx.x & 63;
    const int half = lane >> 5;     // which edge of a pair
    const int cl = lane & 31;       // 8-short chunk within message row
    const int wv = (blockIdx.x * blockDim.x + threadIdx.x) >> 6;
    const int nw = (gridDim.x * blockDim.x) >> 6;
    const size_t plane = (size_t)M * DIM;

    for (int d = wv; d < M; d += nw) {
        const int beg = rowptr[d], end = rowptr[d + 1];
        float acc[8];
#pragma unroll
        for (int j = 0; j < 8; j++) acc[j] = 0.f;

        for (int c0 = beg; c0 < end; c0 += 64) {
            const int n = min(64, end - c0);
            const unsigned myep = (c0 + lane < end) ? ep[c0 + lane] : 0u;
            // 4 edges per iteration: each half-wave issues 2 independent loads
            for (int i = 0; i < n; i += 4) {
                const int i0 = i + half;
                const int i1 = i + 2 + half;
                const unsigned p0 = __shfl(myep, i0 & 63);
                const unsigned p1 = __shfl(myep, i1 & 63);
                // loads always address-safe (myep==0 for OOB lanes)
                const short8_t u0 = *(const short8_t*)(
                    yall + (size_t)(p0 >> 16) * plane +
                    (size_t)(p0 & 0xFFFFu) * DIM + cl * 8);
                const short8_t u1 = *(const short8_t*)(
                    yall + (size_t)(p1 >> 16) * plane +
                    (size_t)(p1 & 0xFFFFu) * DIM + cl * 8);
                if (i0 < n) {
#pragma unroll
                    for (int j = 0; j < 8; j++)
                        acc[j] += bf2f((unsigned short)u0[j]);
                }
                if (i1 < n) {
#pragma unroll
                    for (int j = 0; j < 8; j++)
                        acc[j] += bf2f((unsigned short)u1[j]);
                }
            }
        }
        // fold the two halves: lane l (<32) adds lane l+32's accumulator
        float o[8];
#pragma unroll
        for (int j = 0; j < 8; j++)
            o[j] = acc[j] + __shfl(acc[j], (lane + 32) & 63);
        if (lane < 32) {
            OT* dp = out + (size_t)d * DIM + cl * 8;
            if (sizeof(OT) == 4) {
                *(float4*)((float*)dp) = make_float4(o[0], o[1], o[2], o[3]);
                *(float4*)((float*)dp + 4) = make_float4(o[4], o[5], o[6], o[7]);
            } else {
                short8_t v;
#pragma unroll
                for (int j = 0; j < 8; j++) v[j] = (short)f2bf(o[j]);
                *(short8_t*)((unsigned short*)dp) = v;
            }
        }
    }
}

// ---------------- fallback: fp32 vector GEMM + atomic scatter ----------------
__global__ __launch_bounds__(256) void gemm_bias_relu_f32(
    const float* __restrict__ A, const float* __restrict__ B,
    const float* __restrict__ bias, float* __restrict__ Y, int M)
{
    __shared__ float Asf[16][132];
    __shared__ float Bsf[16][128];
    const int t = threadIdx.x;
    const int tx = t & 15, ty = t >> 4;
    const int row0 = blockIdx.x * 128, col0 = blockIdx.y * 128;
    float acc[8][8];
#pragma unroll
    for (int i = 0; i < 8; i++)
#pragma unroll
        for (int j = 0; j < 8; j++) acc[i][j] = 0.f;
    const int arow = t >> 2, akseg = (t & 3) * 4;
    const int bk0 = t >> 5, bcol = (t & 31) * 4;
    for (int k0 = 0; k0 < DIM; k0 += 16) {
#pragma unroll
        for (int h = 0; h < 2; h++) {
            const int row = row0 + arow + h * 64;
            float4 av = (row < M) ? *(const float4*)(A + (size_t)row * DIM + k0 + akseg)
                                  : make_float4(0, 0, 0, 0);
            Asf[akseg + 0][arow + h * 64] = av.x;
            Asf[akseg + 1][arow + h * 64] = av.y;
            Asf[akseg + 2][arow + h * 64] = av.z;
            Asf[akseg + 3][arow + h * 64] = av.w;
        }
#pragma unroll
        for (int h = 0; h < 2; h++) {
            const int krow = bk0 + h * 8;
            *(float4*)&Bsf[krow][bcol] =
                *(const float4*)(B + (size_t)(k0 + krow) * DIM + col0 + bcol);
        }
        __syncthreads();
#pragma unroll
        for (int k = 0; k < 16; k++) {
            float a[8], b[8];
            *(float4*)&a[0] = *(const float4*)&Asf[k][ty * 4];
            *(float4*)&a[4] = *(const float4*)&Asf[k][64 + ty * 4];
            *(float4*)&b[0] = *(const float4*)&Bsf[k][tx * 4];
            *(float4*)&b[4] = *(const float4*)&Bsf[k][64 + tx * 4];
#pragma unroll
            for (int i = 0; i < 8; i++)
#pragma unroll
                for (int j = 0; j < 8; j++) acc[i][j] = fmaf(a[i], b[j], acc[i][j]);
        }
        __syncthreads();
    }
#pragma unroll
    for (int im = 0; im < 2; im++)
#pragma unroll
        for (int i = 0; i < 4; i++) {
            const int row = row0 + im * 64 + ty * 4 + i;
            if (row >= M) continue;
#pragma unroll
            for (int jm = 0; jm < 2; jm++) {
                const int col = col0 + jm * 64 + tx * 4;
                const float4 bb = *(const float4*)(bias + col);
                float4 o;
                o.x = fmaxf(acc[im * 4 + i][jm * 4 + 0] + bb.x, 0.f);
                o.y = fmaxf(acc[im * 4 + i][jm * 4 + 1] + bb.y, 0.f);
                o.z = fmaxf(acc[im * 4 + i][jm * 4 + 2] + bb.z, 0.f);
                o.w = fmaxf(acc[im * 4 + i][jm * 4 + 3] + bb.w, 0.f);
                *(float4*)(Y + (size_t)row * DIM + col) = o;
            }
        }
}

__global__ __launch_bounds__(256) void scatter_rel(
    const float* __restrict__ y, const int* __restrict__ src,
    const int* __restrict__ dst, const int* __restrict__ et,
    int rel, float* __restrict__ out, int n_edges)
{
    const int lane = threadIdx.x & 63;
    const int wave = (blockIdx.x * blockDim.x + threadIdx.x) >> 6;
    const int nwaves = (gridDim.x * blockDim.x) >> 6;
    for (int e = wave; e < n_edges; e += nwaves) {
        if (et[e] != rel) continue;
        const float4 v = *(const float4*)(y + (size_t)src[e] * DIM + lane * 4);
        float* o = out + (size_t)dst[e] * DIM + lane * 4;
        atomicAdd(o + 0, v.x);
        atomicAdd(o + 1, v.y);
        atomicAdd(o + 2, v.z);
        atomicAdd(o + 3, v.w);
    }
}

static inline size_t align16(size_t x) { return (x + 15) & ~(size_t)15; }

extern "C" void kernel_launch(void* const* d_in, const int* in_sizes, int n_in,
                              void* d_out, int out_size, void* d_ws, size_t ws_size,
                              hipStream_t stream)
{
    const float* x  = (const float*)d_in[0];
    const float* W0 = (const float*)d_in[1];
    const float* b0 = (const float*)d_in[2];
    const float* W1 = (const float*)d_in[3];
    const float* b1 = (const float*)d_in[4];
    const int* eidx = (const int*)d_in[5];
    const int* etyp = (const int*)d_in[6];

    const int M = in_sizes[0] / DIM;   // 50000
    const int E = in_sizes[6];         // 800000
    const int* src = eidx;
    const int* dst = eidx + E;
    float* out = (float*)d_out;

    const size_t plane = (size_t)M * DIM;
    const size_t wbytes = (size_t)N_REL * DIM * DIM * 2;

    const size_t need = align16(plane * 2)              // h1b
                      + align16(plane * 2)              // xb
                      + 2 * align16(wbytes)             // Wt0b, Wt1b
                      + align16((size_t)(M + 1) * 4)    // rowptr
                      + 2 * align16((size_t)M * 4)      // cnt, cursor
                      + align16((size_t)E * 4)          // ep
                      + align16((size_t)N_REL * plane * 2);  // yall

    if (M < 65536 && ws_size >= need) {
        char* ws = (char*)d_ws;
        size_t off = 0;
        unsigned short* h1b  = (unsigned short*)(ws + off); off = align16(off + plane * 2);
        unsigned short* xb   = (unsigned short*)(ws + off); off = align16(off + plane * 2);
        unsigned short* Wt0b = (unsigned short*)(ws + off); off = align16(off + wbytes);
        unsigned short* Wt1b = (unsigned short*)(ws + off); off = align16(off + wbytes);
        int* rowptr = (int*)(ws + off); off = align16(off + (size_t)(M + 1) * 4);
        int* cnt    = (int*)(ws + off); off = align16(off + (size_t)M * 4);
        int* cursor = (int*)(ws + off); off = align16(off + (size_t)M * 4);
        unsigned* ep = (unsigned*)(ws + off); off = align16(off + (size_t)E * 4);
        unsigned short* yall = (unsigned short*)(ws + off);

        // CSR build (shared by both layers)
        hipMemsetAsync(cnt, 0, (size_t)M * 4, stream);
        count_dst<<<(E + 255) / 256, 256, 0, stream>>>(dst, E, cnt);
        scan_counts<<<1, 1024, 0, stream>>>(cnt, M, rowptr, cursor);
        fill_edges<<<(E + 255) / 256, 256, 0, stream>>>(src, dst, etyp, E, cursor, ep);

        // prep: casts / transposes
        cast_f32_bf16<<<(int)((plane / 4 + 255) / 256), 256, 0, stream>>>(
            x, xb, (int)(plane / 4));
        transpose_cast_w<<<dim3(8, 8, N_REL), dim3(32, 8), 0, stream>>>(W0, Wt0b);
        transpose_cast_w<<<dim3(8, 8, N_REL), dim3(32, 8), 0, stream>>>(W1, Wt1b);

        const int Rtiles = (M + 127) / 128;
        const int octets = (Rtiles + 7) / 8;
        const int ggrid = octets * 16 * 8;
        const int agrid = (int)(((size_t)M * 64 + 255) / 256); // 1 wave/dst

        // layer 1
        gemm_mfma_bias_relu<<<ggrid, 256, 0, stream>>>(xb, Wt0b, b0, yall, M, Rtiles);
        aggregate4<unsigned short><<<agrid, 256, 0, stream>>>(yall, ep, rowptr, h1b, M);
        // layer 2
        gemm_mfma_bias_relu<<<ggrid, 256, 0, stream>>>(h1b, Wt1b, b1, yall, M, Rtiles);
        aggregate4<float><<<agrid, 256, 0, stream>>>(yall, ep, rowptr, out, M);
    } else {
        // fallback: fp32 per-relation GEMM + atomic scatter
        float* h1 = (float*)d_ws;
        float* y  = (float*)d_ws + plane;
        const dim3 gblk(256), ggrid2((M + 127) / 128, DIM / 128);
        hipMemsetAsync(h1, 0, plane * 4, stream);
        for (int r = 0; r < N_REL; r++) {
            gemm_bias_relu_f32<<<ggrid2, gblk, 0, stream>>>(
                x, W0 + (size_t)r * DIM * DIM, b0, y, M);
            scatter_rel<<<1024, 256, 0, stream>>>(y, src, dst, etyp, r, h1, E);
        }
        hipMemsetAsync(out, 0, plane * 4, stream);
        for (int r = 0; r < N_REL; r++) {
            gemm_bias_relu_f32<<<ggrid2, gblk, 0, stream>>>(
                h1, W1 + (size_t)r * DIM * DIM, b1, y, M);
            scatter_rel<<<1024, 256, 0, stream>>>(y, src, dst, etyp, r, out, E);
        }
    }
}